// Round 3
// baseline (186.204 us; speedup 1.0000x reference)
//
#include <hip/hip_runtime.h>

#define D_MODEL 1024
#define NUM_HEADS 16
#define DH 64
#define B_SZ 2
#define T_SZ 2048
#define M_ROWS (B_SZ * T_SZ)   // 4096

typedef __bf16 bf16;
typedef __bf16 bf16x4 __attribute__((ext_vector_type(4)));
typedef __bf16 bf16x8 __attribute__((ext_vector_type(8)));
typedef float f32x4 __attribute__((ext_vector_type(4)));

__device__ __forceinline__ void async_copy16(const bf16* g, bf16* l) {
  __builtin_amdgcn_global_load_lds(
      (const __attribute__((address_space(1))) void*)g,
      (__attribute__((address_space(3))) void*)l, 16, 0, 0);
}

// ---------------------------------------------------------------------------
// 1. Cast fp32 -> bf16
// ---------------------------------------------------------------------------
#define NX (M_ROWS * D_MODEL / 4)
#define NW (D_MODEL * D_MODEL / 4)

__global__ __launch_bounds__(256) void cast_all(
    const float* __restrict__ X, const float* __restrict__ Wq,
    const float* __restrict__ Wk, const float* __restrict__ Wv,
    const float* __restrict__ Wo,
    bf16* __restrict__ Xb, bf16* __restrict__ Wqb, bf16* __restrict__ Wkb,
    bf16* __restrict__ Wvb, bf16* __restrict__ Wob) {
  int i = blockIdx.x * 256 + threadIdx.x;
  const float* s; bf16* d; int off;
  if (i < NX) {
    s = X; d = Xb; off = i;
  } else {
    int j = i - NX;
    int w = j >> 18;
    off = j & (NW - 1);
    if (w == 0)      { s = Wq; d = Wqb; }
    else if (w == 1) { s = Wk; d = Wkb; }
    else if (w == 2) { s = Wv; d = Wvb; }
    else             { s = Wo; d = Wob; }
  }
  float4 v = ((const float4*)s)[off];
  bf16x4 o;
  o[0] = (bf16)v.x; o[1] = (bf16)v.y; o[2] = (bf16)v.z; o[3] = (bf16)v.w;
  ((bf16x4*)d)[off] = o;
}

// ---------------------------------------------------------------------------
// 2. QKV GEMM, m97 structure, fused epilogues:
//    sel==1 (K): RoPE on fp32 acc before bf16 store (pairs = adjacent lanes).
//    sel==2 (V): transpose via LDS (reusing As/Bs, XOR-swizzled) then
//                coalesced bf16x8 stores along t into VT. Replaces the
//                scatter 8B/4KB-stride stores that cost ~13us in R1.
// ---------------------------------------------------------------------------
#define KLN 0.28782313662425f   // ln(10000)/32

__global__ __launch_bounds__(256) void qkv_gemm(
    const bf16* __restrict__ Xb,
    const bf16* __restrict__ Wqb, const bf16* __restrict__ Wkb,
    const bf16* __restrict__ Wvb, const int* __restrict__ pos,
    bf16* __restrict__ Q, bf16* __restrict__ K, bf16* __restrict__ VT) {
  __shared__ bf16 S[128 * 64];           // 16KB: As | Bs, reused for V-transpose
  bf16* As = S;
  bf16* Bs = S + 128 * 32;

  int tid = threadIdx.x;
  int wave = tid >> 6, lane = tid & 63;
  int wm = wave >> 1, wn = wave & 1;
  int l15 = lane & 15, quad = lane >> 4;

  int row0 = blockIdx.x * 128;
  int col0 = blockIdx.y * 128;
  int sel = col0 >> 10;
  int nb = col0 & 1023;
  const bf16* W;
  if (sel == 0)      W = Wqb;
  else if (sel == 1) W = Wkb;
  else               W = Wvb;

  int srow = tid >> 2;
  int schunk = tid & 3;
  const bf16* Ag = Xb + (size_t)(row0 + srow) * D_MODEL + schunk * 8;
  const bf16* Bg = W + (size_t)(nb + srow) * D_MODEL + schunk * 8;
  bf16* Al0 = &As[srow * 32 + schunk * 8];
  bf16* Al1 = &As[(srow + 64) * 32 + schunk * 8];
  bf16* Bl0 = &Bs[srow * 32 + schunk * 8];
  bf16* Bl1 = &Bs[(srow + 64) * 32 + schunk * 8];

  f32x4 acc[4][4];
#pragma unroll
  for (int i = 0; i < 4; ++i)
#pragma unroll
    for (int j = 0; j < 4; ++j) acc[i][j] = (f32x4){0.f, 0.f, 0.f, 0.f};

  for (int k0 = 0; k0 < D_MODEL; k0 += 32) {
    async_copy16(Ag + k0, Al0);
    async_copy16(Ag + k0 + (size_t)64 * D_MODEL, Al1);
    async_copy16(Bg + k0, Bl0);
    async_copy16(Bg + k0 + (size_t)64 * D_MODEL, Bl1);
    __syncthreads();

    bf16x8 af[4], bfr[4];
#pragma unroll
    for (int i = 0; i < 4; ++i)
      af[i] = *(const bf16x8*)&As[(wm * 64 + i * 16 + l15) * 32 + quad * 8];
#pragma unroll
    for (int j = 0; j < 4; ++j)
      bfr[j] = *(const bf16x8*)&Bs[(wn * 64 + j * 16 + l15) * 32 + quad * 8];
#pragma unroll
    for (int i = 0; i < 4; ++i)
#pragma unroll
      for (int j = 0; j < 4; ++j)
        acc[i][j] = __builtin_amdgcn_mfma_f32_16x16x32_bf16(af[i], bfr[j],
                                                            acc[i][j], 0, 0, 0);
    __syncthreads();
  }

  if (sel == 1) {
    // ---- fused K-RoPE on fp32 accumulator ----
    float pv[4][4];
#pragma unroll
    for (int i = 0; i < 4; ++i)
#pragma unroll
      for (int r = 0; r < 4; ++r)
        pv[i][r] =
            (float)pos[(row0 + wm * 64 + i * 16 + quad * 4 + r) & (T_SZ - 1)];
    bool even = (l15 & 1) == 0;
#pragma unroll
    for (int j = 0; j < 4; ++j) {
      // pair index within head: same for both lanes of a pair
      float fr = __expf(-(float)((j * 16 + (l15 & 14)) >> 1) * KLN);
#pragma unroll
      for (int i = 0; i < 4; ++i)
#pragma unroll
        for (int r = 0; r < 4; ++r) {
          float v = acc[i][j][r];
          float pn = __shfl_xor(v, 1);
          float s, c;
          __sincosf(pv[i][r] * fr, &s, &c);
          acc[i][j][r] = even ? (v * c - pn * s) : (pn * s + v * c);
        }
    }
  }

  if (sel == 2) {
    // ---- V transposed via LDS, coalesced stores into VT ----
    int b = row0 >> 11;
    int t0 = row0 & (T_SZ - 1);
    int h0 = nb >> 6;                    // wn-half p covers head h0+p entirely
#pragma unroll
    for (int p = 0; p < 2; ++p) {
      __syncthreads();                   // S free for this pass
      if (wn == p) {
#pragma unroll
        for (int i = 0; i < 4; ++i) {
          int t = wm * 64 + i * 16 + quad * 4;
#pragma unroll
          for (int j = 0; j < 4; ++j) {
            int d = j * 16 + l15;
            bf16x4 ov;
#pragma unroll
            for (int r = 0; r < 4; ++r) ov[r] = (bf16)acc[i][j][r];
            *(bf16x4*)&S[d * 128 + (t ^ ((d & 7) << 3))] = ov;
          }
        }
      }
      __syncthreads();                   // tile ready
      int d = tid >> 2;                  // 0..63
      int c = (tid & 3) * 8;             // t-group base within 32
      size_t vbase = ((size_t)(b * NUM_HEADS + h0 + p) * DH + d) * T_SZ + t0;
#pragma unroll
      for (int tt = 0; tt < 128; tt += 32) {
        int t = tt + c;
        bf16x8 ov = *(const bf16x8*)&S[d * 128 + (t ^ ((d & 7) << 3))];
        *(bf16x8*)&VT[vbase + t] = ov;
      }
    }
  } else {
    bf16* Out = (sel == 0) ? Q : K;
#pragma unroll
    for (int i = 0; i < 4; ++i) {
      int row = row0 + wm * 64 + i * 16 + quad * 4;
#pragma unroll
      for (int j = 0; j < 4; ++j) {
        int col = nb + wn * 64 + j * 16 + l15;
#pragma unroll
        for (int r = 0; r < 4; ++r)
          Out[(size_t)(row + r) * D_MODEL + col] = (bf16)acc[i][j][r];
      }
    }
  }
}

// ---------------------------------------------------------------------------
// 3. Causal flash attention (verified 45.6us version: 64-row q-tiles,
//    1024 blocks, wave owns 16 rows -> max wave-level parallelism).
// ---------------------------------------------------------------------------
#define PST 72
#define KST 72

__global__ __launch_bounds__(256) void attn_kernel(
    const bf16* __restrict__ Q, const bf16* __restrict__ K,
    const bf16* __restrict__ VT, const int* __restrict__ pos,
    bf16* __restrict__ AO) {
  __shared__ bf16 Kt[64 * KST];          // K rows (kv), d 0..63, stride 72
  __shared__ bf16 Vt[64 * KST];          // VT rows (d), c 0..63, stride 72
  __shared__ bf16 Pbuf[4][16 * PST];

  int bh = blockIdx.x;                   // 0..31
  int qi = 31 - (int)blockIdx.y;         // q-tile of 64, heavy first
  int bb = bh >> 4, h = bh & 15;
  int tid = threadIdx.x;
  int wave = tid >> 6, lane = tid & 63;
  int l15 = lane & 15, quad = lane >> 4;

  int q0 = qi * 64 + wave * 16;
  size_t grow = (size_t)bb * T_SZ + q0;

  // ---- Q fragments + in-register RoPE (pairs are in-lane) ----
  const bf16* Qp = Q + (grow + l15) * D_MODEL + h * DH + quad * 8;
  bf16x8 bq0 = *(const bf16x8*)(Qp);
  bf16x8 bq1 = *(const bf16x8*)(Qp + 32);
  {
    float p = (float)pos[q0 + l15];
#pragma unroll
    for (int jj = 0; jj < 4; ++jj) {
      int i0 = quad * 4 + jj;
      float s, c;
      __sincosf(p * __expf(-(float)i0 * KLN), &s, &c);
      float x1 = (float)bq0[2 * jj], x2 = (float)bq0[2 * jj + 1];
      bq0[2 * jj]     = (bf16)(x1 * c - x2 * s);
      bq0[2 * jj + 1] = (bf16)(x1 * s + x2 * c);
      __sincosf(p * __expf(-(float)(i0 + 16) * KLN), &s, &c);
      float y1 = (float)bq1[2 * jj], y2 = (float)bq1[2 * jj + 1];
      bq1[2 * jj]     = (bf16)(y1 * c - y2 * s);
      bq1[2 * jj + 1] = (bf16)(y1 * s + y2 * c);
    }
  }

  f32x4 o[4];
#pragma unroll
  for (int nt = 0; nt < 4; ++nt) o[nt] = (f32x4){0.f, 0.f, 0.f, 0.f};
  float l_i = 0.f;

  // ---- staging: thread covers K row tid>>2 (16 d-elems) + same for VT ----
  int srow = tid >> 2;                   // 0..63
  int sc = (tid & 3) * 16;               // elem col base (32 B per thread)
  const bf16* Kg = K + ((size_t)bb * T_SZ + srow) * D_MODEL + h * DH + sc;
  const bf16* Vg = VT + ((size_t)bh * DH + srow) * T_SZ + sc;
  bf16* Kl = &Kt[srow * KST + sc];
  bf16* Vl = &Vt[srow * KST + sc];

  bf16* Pw = Pbuf[wave];
  int nchunks = qi + 1;
  int rel = wave * 16 + l15;             // causal boundary (last chunk)

  // prefetch chunk 0
  bf16x8 kr0 = *(const bf16x8*)(Kg);
  bf16x8 kr1 = *(const bf16x8*)(Kg + 8);
  bf16x8 vr0 = *(const bf16x8*)(Vg);
  bf16x8 vr1 = *(const bf16x8*)(Vg + 8);

  for (int t = 0; t < nchunks; ++t) {
    __syncthreads();                     // previous compute done; LDS writable
    *(bf16x8*)(Kl) = kr0;
    *(bf16x8*)(Kl + 8) = kr1;
    *(bf16x8*)(Vl) = vr0;
    *(bf16x8*)(Vl + 8) = vr1;
    if (t + 1 < nchunks) {               // prefetch next chunk into registers
      const bf16* Kn = Kg + (size_t)(t + 1) * 64 * D_MODEL;
      const bf16* Vn = Vg + (t + 1) * 64;
      kr0 = *(const bf16x8*)(Kn);
      kr1 = *(const bf16x8*)(Kn + 8);
      vr0 = *(const bf16x8*)(Vn);
      vr1 = *(const bf16x8*)(Vn + 8);
    }
    __syncthreads();                     // tiles ready

    // ---- S^T = K · Q^T ----
    f32x4 st[4];
#pragma unroll
    for (int cs = 0; cs < 4; ++cs) {
      bf16x8 ak0 = *(const bf16x8*)&Kt[(cs * 16 + l15) * KST + quad * 8];
      bf16x8 ak1 = *(const bf16x8*)&Kt[(cs * 16 + l15) * KST + 32 + quad * 8];
      f32x4 s4 = (f32x4){0.f, 0.f, 0.f, 0.f};
      s4 = __builtin_amdgcn_mfma_f32_16x16x32_bf16(ak0, bq0, s4, 0, 0, 0);
      s4 = __builtin_amdgcn_mfma_f32_16x16x32_bf16(ak1, bq1, s4, 0, 0, 0);
      st[cs] = s4;
    }

    // ---- p = exp(s*scale); mask above diagonal on last chunk ----
    bool last = (t == nchunks - 1);
    float ps = 0.f;
#pragma unroll
    for (int cs = 0; cs < 4; ++cs)
#pragma unroll
      for (int r = 0; r < 4; ++r) {
        float p = __expf(st[cs][r] * 0.125f);
        if (last) {
          int cl = cs * 16 + quad * 4 + r;
          p = (cl > rel) ? 0.f : p;
        }
        st[cs][r] = p;
        ps += p;
      }
    l_i += ps;

    // ---- P[q][c] -> per-wave LDS, transpose to B-operand layout ----
#pragma unroll
    for (int cs = 0; cs < 4; ++cs) {
      bf16x4 pk;
#pragma unroll
      for (int r = 0; r < 4; ++r) pk[r] = (bf16)st[cs][r];
      *(bf16x4*)&Pw[l15 * PST + cs * 16 + quad * 4] = pk;
    }
    __asm__ __volatile__("" ::: "memory");
    bf16x8 bp0 = *(const bf16x8*)&Pw[l15 * PST + quad * 8];
    bf16x8 bp1 = *(const bf16x8*)&Pw[l15 * PST + 32 + quad * 8];
    __asm__ __volatile__("" ::: "memory");

    // ---- O^T += V^T · P^T ----
#pragma unroll
    for (int nt = 0; nt < 4; ++nt) {
      bf16x8 av0 = *(const bf16x8*)&Vt[(nt * 16 + l15) * KST + quad * 8];
      bf16x8 av1 = *(const bf16x8*)&Vt[(nt * 16 + l15) * KST + 32 + quad * 8];
      o[nt] = __builtin_amdgcn_mfma_f32_16x16x32_bf16(av0, bp0, o[nt], 0, 0, 0);
      o[nt] = __builtin_amdgcn_mfma_f32_16x16x32_bf16(av1, bp1, o[nt], 0, 0, 0);
    }
  }

  // ---- l reduction across quads, normalize, store ----
  l_i += __shfl_xor(l_i, 16);
  l_i += __shfl_xor(l_i, 32);
  float inv = 1.0f / l_i;
#pragma unroll
  for (int nt = 0; nt < 4; ++nt) {
    bf16x4 ov;
#pragma unroll
    for (int r = 0; r < 4; ++r) ov[r] = (bf16)(o[nt][r] * inv);
    *(bf16x4*)&AO[(grow + l15) * D_MODEL + h * DH + nt * 16 + quad * 4] = ov;
  }
}

// ---------------------------------------------------------------------------
// 4. Output GEMM: 128x64 tiles -> 512 blocks (2/CU instead of 1/CU)
// ---------------------------------------------------------------------------
__global__ __launch_bounds__(256) void out_gemm(
    const bf16* __restrict__ AO, const bf16* __restrict__ Wob,
    float* __restrict__ out) {
  __shared__ bf16 As[128 * 32];
  __shared__ bf16 Bs[64 * 32];

  int tid = threadIdx.x;
  int wave = tid >> 6, lane = tid & 63;
  int l15 = lane & 15, quad = lane >> 4;

  int row0 = blockIdx.x * 128;
  int nb = blockIdx.y * 64;

  int srow = tid >> 2;
  int schunk = tid & 3;
  const bf16* Ag = AO + (size_t)(row0 + srow) * D_MODEL + schunk * 8;
  const bf16* Bg = Wob + (size_t)(nb + srow) * D_MODEL + schunk * 8;
  bf16* Al0 = &As[srow * 32 + schunk * 8];
  bf16* Al1 = &As[(srow + 64) * 32 + schunk * 8];
  bf16* Bl = &Bs[srow * 32 + schunk * 8];

  f32x4 acc[2][4];
#pragma unroll
  for (int i = 0; i < 2; ++i)
#pragma unroll
    for (int j = 0; j < 4; ++j) acc[i][j] = (f32x4){0.f, 0.f, 0.f, 0.f};

  for (int k0 = 0; k0 < D_MODEL; k0 += 32) {
    async_copy16(Ag + k0, Al0);
    async_copy16(Ag + k0 + (size_t)64 * D_MODEL, Al1);
    async_copy16(Bg + k0, Bl);
    __syncthreads();

    bf16x8 af[2], bfr[4];
#pragma unroll
    for (int i = 0; i < 2; ++i)
      af[i] = *(const bf16x8*)&As[(wave * 32 + i * 16 + l15) * 32 + quad * 8];
#pragma unroll
    for (int j = 0; j < 4; ++j)
      bfr[j] = *(const bf16x8*)&Bs[(j * 16 + l15) * 32 + quad * 8];
#pragma unroll
    for (int i = 0; i < 2; ++i)
#pragma unroll
      for (int j = 0; j < 4; ++j)
        acc[i][j] = __builtin_amdgcn_mfma_f32_16x16x32_bf16(af[i], bfr[j],
                                                            acc[i][j], 0, 0, 0);
    __syncthreads();
  }

#pragma unroll
  for (int i = 0; i < 2; ++i) {
    int row = row0 + wave * 32 + i * 16 + quad * 4;
#pragma unroll
    for (int j = 0; j < 4; ++j) {
      int col = nb + j * 16 + l15;
#pragma unroll
      for (int r = 0; r < 4; ++r)
        out[(size_t)(row + r) * D_MODEL + col] = acc[i][j][r];
    }
  }
}

// ---------------------------------------------------------------------------
extern "C" void kernel_launch(void* const* d_in, const int* in_sizes, int n_in,
                              void* d_out, int out_size, void* d_ws, size_t ws_size,
                              hipStream_t stream) {
  const float* X  = (const float*)d_in[0];
  const float* Wq = (const float*)d_in[1];
  const float* Wk = (const float*)d_in[2];
  const float* Wv = (const float*)d_in[3];
  const float* Wo = (const float*)d_in[4];
  const int*  pos = (const int*)d_in[5];
  float* out = (float*)d_out;

  char* w = (char*)d_ws;
  bf16* Xb  = (bf16*)w;  w += (size_t)M_ROWS * D_MODEL * 2;
  bf16* Wqb = (bf16*)w;  w += (size_t)D_MODEL * D_MODEL * 2;
  bf16* Wkb = (bf16*)w;  w += (size_t)D_MODEL * D_MODEL * 2;
  bf16* Wvb = (bf16*)w;  w += (size_t)D_MODEL * D_MODEL * 2;
  bf16* Wob = (bf16*)w;  w += (size_t)D_MODEL * D_MODEL * 2;
  bf16* Qb  = (bf16*)w;  w += (size_t)M_ROWS * D_MODEL * 2;
  bf16* Kb  = (bf16*)w;  w += (size_t)M_ROWS * D_MODEL * 2;
  bf16* VT  = (bf16*)w;  w += (size_t)M_ROWS * D_MODEL * 2;
  bf16* AO  = (bf16*)w;  w += (size_t)M_ROWS * D_MODEL * 2;

  cast_all<<<(NX + 4 * NW) / 256, 256, 0, stream>>>(X, Wq, Wk, Wv, Wo,
                                                    Xb, Wqb, Wkb, Wvb, Wob);
  qkv_gemm<<<dim3(M_ROWS / 128, 3 * D_MODEL / 128), 256, 0, stream>>>(
      Xb, Wqb, Wkb, Wvb, pos, Qb, Kb, VT);
  attn_kernel<<<dim3(B_SZ * NUM_HEADS, T_SZ / 64), 256, 0, stream>>>(
      Qb, Kb, VT, pos, AO);
  out_gemm<<<dim3(M_ROWS / 128, D_MODEL / 64), 256, 0, stream>>>(AO, Wob, out);
}

// Round 4
// 174.914 us; speedup vs baseline: 1.0645x; 1.0645x over previous
//
#include <hip/hip_runtime.h>

#define D_MODEL 1024
#define NUM_HEADS 16
#define DH 64
#define B_SZ 2
#define T_SZ 2048
#define M_ROWS (B_SZ * T_SZ)   // 4096

typedef __bf16 bf16;
typedef __bf16 bf16x4 __attribute__((ext_vector_type(4)));
typedef __bf16 bf16x8 __attribute__((ext_vector_type(8)));
typedef float f32x4 __attribute__((ext_vector_type(4)));

__device__ __forceinline__ void async_copy16(const bf16* g, bf16* l) {
  __builtin_amdgcn_global_load_lds(
      (const __attribute__((address_space(1))) void*)g,
      (__attribute__((address_space(3))) void*)l, 16, 0, 0);
}

// ---------------------------------------------------------------------------
// 1. Cast fp32 -> bf16
// ---------------------------------------------------------------------------
#define NX (M_ROWS * D_MODEL / 4)
#define NW (D_MODEL * D_MODEL / 4)

__global__ __launch_bounds__(256) void cast_all(
    const float* __restrict__ X, const float* __restrict__ Wq,
    const float* __restrict__ Wk, const float* __restrict__ Wv,
    const float* __restrict__ Wo,
    bf16* __restrict__ Xb, bf16* __restrict__ Wqb, bf16* __restrict__ Wkb,
    bf16* __restrict__ Wvb, bf16* __restrict__ Wob) {
  int i = blockIdx.x * 256 + threadIdx.x;
  const float* s; bf16* d; int off;
  if (i < NX) {
    s = X; d = Xb; off = i;
  } else {
    int j = i - NX;
    int w = j >> 18;
    off = j & (NW - 1);
    if (w == 0)      { s = Wq; d = Wqb; }
    else if (w == 1) { s = Wk; d = Wkb; }
    else if (w == 2) { s = Wv; d = Wvb; }
    else             { s = Wo; d = Wob; }
  }
  float4 v = ((const float4*)s)[off];
  bf16x4 o;
  o[0] = (bf16)v.x; o[1] = (bf16)v.y; o[2] = (bf16)v.z; o[3] = (bf16)v.w;
  ((bf16x4*)d)[off] = o;
}

// ---------------------------------------------------------------------------
// 2. QKV GEMM — 256x256 tile, BK=32, 4-deep circular LDS prefetch pipeline
//    (T3/T4/T5: counted vmcnt never drained in-loop, one raw barrier per
//    K-tile, setprio around the MFMA cluster). 8 waves (2M x 4N), each owns
//    a 128x64 output (8x4 fragments). LDS reads XOR-swizzled; the same
//    swizzle is pre-applied to the global source so global_load_lds stays
//    lane-linear (both-sides involution).
//    Race ledger: reads of buf b complete (lgkmcnt 0) before the barrier of
//    their iteration; loads that overwrite b (tile kt+3) are issued only
//    after a later barrier; tile kt+1 is guaranteed landed block-wide by
//    each iteration's vmcnt(8)+barrier.
//    Fused epilogues: sel==1 K-RoPE on fp32 acc (pairs = adjacent lanes),
//    sel==2 V stored transposed (bf16x4 along t; measured cost-free).
// ---------------------------------------------------------------------------
#define KLN 0.28782313662425f   // ln(10000)/32
#define BK 32
#define NKT (D_MODEL / BK)      // 32

__global__ __launch_bounds__(512, 2) void qkv_gemm(
    const bf16* __restrict__ Xb,
    const bf16* __restrict__ Wqb, const bf16* __restrict__ Wkb,
    const bf16* __restrict__ Wvb, const int* __restrict__ pos,
    bf16* __restrict__ Q, bf16* __restrict__ K, bf16* __restrict__ VT) {
  __shared__ bf16 LA[4][256 * BK];     // 4 bufs x 16 KB
  __shared__ bf16 LB[4][256 * BK];     // 4 bufs x 16 KB

  int tid = threadIdx.x;
  int wave = tid >> 6, lane = tid & 63;
  int wm = wave >> 2, wn = wave & 3;   // 2 x 4 wave grid
  int l15 = lane & 15, quad = lane >> 4;

  int row0 = blockIdx.x * 256;
  int col0 = blockIdx.y * 256;
  int sel = col0 >> 10;
  int nb = col0 & 1023;
  const bf16* W = (sel == 0) ? Wqb : (sel == 1) ? Wkb : Wvb;

  // staging: thread covers rows tid>>2 and tid>>2+128, slot tid&3 (16 B),
  // source column pre-swizzled so linear LDS == swizzled layout
  int srow = tid >> 2;
  int scol = 8 * ((tid & 3) ^ ((tid >> 3) & 3));
  const bf16* Ag = Xb + (size_t)(row0 + srow) * D_MODEL + scol;
  const bf16* Bg = W + (size_t)(nb + srow) * D_MODEL + scol;
  int ldst = tid * 8;                  // LDS elem offset, load 0

  // fragment read bases (slot = quad ^ ((row>>1)&3); mi*16 doesn't change it)
  int swz = 8 * (quad ^ ((l15 >> 1) & 3));
  int aoff = (wm * 128 + l15) * BK + swz;
  int boff = (wn * 64 + l15) * BK + swz;

  f32x4 acc[8][4];
#pragma unroll
  for (int mi = 0; mi < 8; ++mi)
#pragma unroll
    for (int nj = 0; nj < 4; ++nj) acc[mi][nj] = (f32x4){0.f, 0.f, 0.f, 0.f};

  // prologue: stage tiles 0,1,2
#pragma unroll
  for (int pt = 0; pt < 3; ++pt) {
    int k0 = pt * BK;
    async_copy16(Ag + k0, &LA[pt][ldst]);
    async_copy16(Ag + k0 + (size_t)128 * D_MODEL, &LA[pt][ldst + 4096]);
    async_copy16(Bg + k0, &LB[pt][ldst]);
    async_copy16(Bg + k0 + (size_t)128 * D_MODEL, &LB[pt][ldst + 4096]);
  }
  asm volatile("s_waitcnt vmcnt(8)" ::: "memory");   // tile 0 landed
  __builtin_amdgcn_s_barrier();
  __builtin_amdgcn_sched_barrier(0);

  for (int kt = 0; kt < NKT; ++kt) {
    const bf16* La = LA[kt & 3];
    const bf16* Lb = LB[kt & 3];
    bf16x8 a[8], b[4];
#pragma unroll
    for (int mi = 0; mi < 8; ++mi)
      a[mi] = *(const bf16x8*)&La[aoff + mi * 16 * BK];
#pragma unroll
    for (int nj = 0; nj < 4; ++nj)
      b[nj] = *(const bf16x8*)&Lb[boff + nj * 16 * BK];

    if (kt < NKT - 3) {                // stage tile kt+3 into buf (kt-1)&3
      int k0 = (kt + 3) * BK;
      int bq = (kt + 3) & 3;
      async_copy16(Ag + k0, &LA[bq][ldst]);
      async_copy16(Ag + k0 + (size_t)128 * D_MODEL, &LA[bq][ldst + 4096]);
      async_copy16(Bg + k0, &LB[bq][ldst]);
      async_copy16(Bg + k0 + (size_t)128 * D_MODEL, &LB[bq][ldst + 4096]);
      asm volatile("s_waitcnt vmcnt(8) lgkmcnt(0)" ::: "memory");
    } else {
      asm volatile("s_waitcnt vmcnt(0) lgkmcnt(0)" ::: "memory");
    }
    __builtin_amdgcn_s_barrier();
    __builtin_amdgcn_sched_barrier(0);

    __builtin_amdgcn_s_setprio(1);
#pragma unroll
    for (int mi = 0; mi < 8; ++mi)
#pragma unroll
      for (int nj = 0; nj < 4; ++nj)
        acc[mi][nj] = __builtin_amdgcn_mfma_f32_16x16x32_bf16(
            a[mi], b[nj], acc[mi][nj], 0, 0, 0);
    __builtin_amdgcn_s_setprio(0);
  }

  // ---- epilogues ----
  if (sel == 1) {
    // fused K-RoPE on fp32 accumulator; pairs are adjacent lanes (cols)
    bool even = (l15 & 1) == 0;
#pragma unroll
    for (int nj = 0; nj < 4; ++nj) {
      float fr = __expf(-(float)((nj * 16 + (l15 & 14)) >> 1) * KLN);
#pragma unroll
      for (int mi = 0; mi < 8; ++mi)
#pragma unroll
        for (int r = 0; r < 4; ++r) {
          float p = (float)pos[(row0 + wm * 128 + mi * 16 + quad * 4 + r) &
                               (T_SZ - 1)];
          float v = acc[mi][nj][r];
          float pn = __shfl_xor(v, 1);
          float s, c;
          __sincosf(p * fr, &s, &c);
          acc[mi][nj][r] = even ? (v * c - pn * s) : (pn * s + v * c);
        }
    }
  }

  if (sel == 2) {
    // V stored directly transposed: VT[(b*16+h)*64+d][t], r packs along t
    int b = row0 >> 11;
    int t0 = row0 & (T_SZ - 1);
#pragma unroll
    for (int mi = 0; mi < 8; ++mi) {
      int t = t0 + wm * 128 + mi * 16 + quad * 4;
#pragma unroll
      for (int nj = 0; nj < 4; ++nj) {
        int col = nb + wn * 64 + nj * 16 + l15;
        int h = col >> 6;
        int d = col & 63;
        bf16x4 ov;
#pragma unroll
        for (int r = 0; r < 4; ++r) ov[r] = (bf16)acc[mi][nj][r];
        *(bf16x4*)&VT[((size_t)(b * NUM_HEADS + h) * DH + d) * T_SZ + t] = ov;
      }
    }
  } else {
    bf16* Out = (sel == 0) ? Q : K;
#pragma unroll
    for (int mi = 0; mi < 8; ++mi) {
      int row = row0 + wm * 128 + mi * 16 + quad * 4;
#pragma unroll
      for (int nj = 0; nj < 4; ++nj) {
        int col = nb + wn * 64 + nj * 16 + l15;
#pragma unroll
        for (int r = 0; r < 4; ++r)
          Out[(size_t)(row + r) * D_MODEL + col] = (bf16)acc[mi][nj][r];
      }
    }
  }
}

// ---------------------------------------------------------------------------
// 3. Causal flash attention (verified 45.6us version: 64-row q-tiles,
//    1024 blocks, wave owns 16 rows -> max wave-level parallelism).
// ---------------------------------------------------------------------------
#define PST 72
#define KST 72

__global__ __launch_bounds__(256) void attn_kernel(
    const bf16* __restrict__ Q, const bf16* __restrict__ K,
    const bf16* __restrict__ VT, const int* __restrict__ pos,
    bf16* __restrict__ AO) {
  __shared__ bf16 Kt[64 * KST];          // K rows (kv), d 0..63, stride 72
  __shared__ bf16 Vt[64 * KST];          // VT rows (d), c 0..63, stride 72
  __shared__ bf16 Pbuf[4][16 * PST];

  int bh = blockIdx.x;                   // 0..31
  int qi = 31 - (int)blockIdx.y;         // q-tile of 64, heavy first
  int bb = bh >> 4, h = bh & 15;
  int tid = threadIdx.x;
  int wave = tid >> 6, lane = tid & 63;
  int l15 = lane & 15, quad = lane >> 4;

  int q0 = qi * 64 + wave * 16;
  size_t grow = (size_t)bb * T_SZ + q0;

  // ---- Q fragments + in-register RoPE (pairs are in-lane) ----
  const bf16* Qp = Q + (grow + l15) * D_MODEL + h * DH + quad * 8;
  bf16x8 bq0 = *(const bf16x8*)(Qp);
  bf16x8 bq1 = *(const bf16x8*)(Qp + 32);
  {
    float p = (float)pos[q0 + l15];
#pragma unroll
    for (int jj = 0; jj < 4; ++jj) {
      int i0 = quad * 4 + jj;
      float s, c;
      __sincosf(p * __expf(-(float)i0 * KLN), &s, &c);
      float x1 = (float)bq0[2 * jj], x2 = (float)bq0[2 * jj + 1];
      bq0[2 * jj]     = (bf16)(x1 * c - x2 * s);
      bq0[2 * jj + 1] = (bf16)(x1 * s + x2 * c);
      __sincosf(p * __expf(-(float)(i0 + 16) * KLN), &s, &c);
      float y1 = (float)bq1[2 * jj], y2 = (float)bq1[2 * jj + 1];
      bq1[2 * jj]     = (bf16)(y1 * c - y2 * s);
      bq1[2 * jj + 1] = (bf16)(y1 * s + y2 * c);
    }
  }

  f32x4 o[4];
#pragma unroll
  for (int nt = 0; nt < 4; ++nt) o[nt] = (f32x4){0.f, 0.f, 0.f, 0.f};
  float l_i = 0.f;

  // ---- staging: thread covers K row tid>>2 (16 d-elems) + same for VT ----
  int srow = tid >> 2;                   // 0..63
  int sc = (tid & 3) * 16;               // elem col base (32 B per thread)
  const bf16* Kg = K + ((size_t)bb * T_SZ + srow) * D_MODEL + h * DH + sc;
  const bf16* Vg = VT + ((size_t)bh * DH + srow) * T_SZ + sc;
  bf16* Kl = &Kt[srow * KST + sc];
  bf16* Vl = &Vt[srow * KST + sc];

  bf16* Pw = Pbuf[wave];
  int nchunks = qi + 1;
  int rel = wave * 16 + l15;             // causal boundary (last chunk)

  // prefetch chunk 0
  bf16x8 kr0 = *(const bf16x8*)(Kg);
  bf16x8 kr1 = *(const bf16x8*)(Kg + 8);
  bf16x8 vr0 = *(const bf16x8*)(Vg);
  bf16x8 vr1 = *(const bf16x8*)(Vg + 8);

  for (int t = 0; t < nchunks; ++t) {
    __syncthreads();                     // previous compute done; LDS writable
    *(bf16x8*)(Kl) = kr0;
    *(bf16x8*)(Kl + 8) = kr1;
    *(bf16x8*)(Vl) = vr0;
    *(bf16x8*)(Vl + 8) = vr1;
    if (t + 1 < nchunks) {               // prefetch next chunk into registers
      const bf16* Kn = Kg + (size_t)(t + 1) * 64 * D_MODEL;
      const bf16* Vn = Vg + (t + 1) * 64;
      kr0 = *(const bf16x8*)(Kn);
      kr1 = *(const bf16x8*)(Kn + 8);
      vr0 = *(const bf16x8*)(Vn);
      vr1 = *(const bf16x8*)(Vn + 8);
    }
    __syncthreads();                     // tiles ready

    // ---- S^T = K · Q^T ----
    f32x4 st[4];
#pragma unroll
    for (int cs = 0; cs < 4; ++cs) {
      bf16x8 ak0 = *(const bf16x8*)&Kt[(cs * 16 + l15) * KST + quad * 8];
      bf16x8 ak1 = *(const bf16x8*)&Kt[(cs * 16 + l15) * KST + 32 + quad * 8];
      f32x4 s4 = (f32x4){0.f, 0.f, 0.f, 0.f};
      s4 = __builtin_amdgcn_mfma_f32_16x16x32_bf16(ak0, bq0, s4, 0, 0, 0);
      s4 = __builtin_amdgcn_mfma_f32_16x16x32_bf16(ak1, bq1, s4, 0, 0, 0);
      st[cs] = s4;
    }

    // ---- p = exp(s*scale); mask above diagonal on last chunk ----
    bool last = (t == nchunks - 1);
    float ps = 0.f;
#pragma unroll
    for (int cs = 0; cs < 4; ++cs)
#pragma unroll
      for (int r = 0; r < 4; ++r) {
        float p = __expf(st[cs][r] * 0.125f);
        if (last) {
          int cl = cs * 16 + quad * 4 + r;
          p = (cl > rel) ? 0.f : p;
        }
        st[cs][r] = p;
        ps += p;
      }
    l_i += ps;

    // ---- P[q][c] -> per-wave LDS, transpose to B-operand layout ----
#pragma unroll
    for (int cs = 0; cs < 4; ++cs) {
      bf16x4 pk;
#pragma unroll
      for (int r = 0; r < 4; ++r) pk[r] = (bf16)st[cs][r];
      *(bf16x4*)&Pw[l15 * PST + cs * 16 + quad * 4] = pk;
    }
    __asm__ __volatile__("" ::: "memory");
    bf16x8 bp0 = *(const bf16x8*)&Pw[l15 * PST + quad * 8];
    bf16x8 bp1 = *(const bf16x8*)&Pw[l15 * PST + 32 + quad * 8];
    __asm__ __volatile__("" ::: "memory");

    // ---- O^T += V^T · P^T ----
#pragma unroll
    for (int nt = 0; nt < 4; ++nt) {
      bf16x8 av0 = *(const bf16x8*)&Vt[(nt * 16 + l15) * KST + quad * 8];
      bf16x8 av1 = *(const bf16x8*)&Vt[(nt * 16 + l15) * KST + 32 + quad * 8];
      o[nt] = __builtin_amdgcn_mfma_f32_16x16x32_bf16(av0, bp0, o[nt], 0, 0, 0);
      o[nt] = __builtin_amdgcn_mfma_f32_16x16x32_bf16(av1, bp1, o[nt], 0, 0, 0);
    }
  }

  // ---- l reduction across quads, normalize, store ----
  l_i += __shfl_xor(l_i, 16);
  l_i += __shfl_xor(l_i, 32);
  float inv = 1.0f / l_i;
#pragma unroll
  for (int nt = 0; nt < 4; ++nt) {
    bf16x4 ov;
#pragma unroll
    for (int r = 0; r < 4; ++r) ov[r] = (bf16)(o[nt][r] * inv);
    *(bf16x4*)&AO[(grow + l15) * D_MODEL + h * DH + nt * 16 + quad * 4] = ov;
  }
}

// ---------------------------------------------------------------------------
// 4. Output GEMM: 128x64 tiles -> 512 blocks (2/CU instead of 1/CU)
// ---------------------------------------------------------------------------
__global__ __launch_bounds__(256) void out_gemm(
    const bf16* __restrict__ AO, const bf16* __restrict__ Wob,
    float* __restrict__ out) {
  __shared__ bf16 As[128 * 32];
  __shared__ bf16 Bs[64 * 32];

  int tid = threadIdx.x;
  int wave = tid >> 6, lane = tid & 63;
  int l15 = lane & 15, quad = lane >> 4;

  int row0 = blockIdx.x * 128;
  int nb = blockIdx.y * 64;

  int srow = tid >> 2;
  int schunk = tid & 3;
  const bf16* Ag = AO + (size_t)(row0 + srow) * D_MODEL + schunk * 8;
  const bf16* Bg = Wob + (size_t)(nb + srow) * D_MODEL + schunk * 8;
  bf16* Al0 = &As[srow * 32 + schunk * 8];
  bf16* Al1 = &As[(srow + 64) * 32 + schunk * 8];
  bf16* Bl = &Bs[srow * 32 + schunk * 8];

  f32x4 acc[2][4];
#pragma unroll
  for (int i = 0; i < 2; ++i)
#pragma unroll
    for (int j = 0; j < 4; ++j) acc[i][j] = (f32x4){0.f, 0.f, 0.f, 0.f};

  for (int k0 = 0; k0 < D_MODEL; k0 += 32) {
    async_copy16(Ag + k0, Al0);
    async_copy16(Ag + k0 + (size_t)64 * D_MODEL, Al1);
    async_copy16(Bg + k0, Bl);
    __syncthreads();

    bf16x8 af[2], bfr[4];
#pragma unroll
    for (int i = 0; i < 2; ++i)
      af[i] = *(const bf16x8*)&As[(wave * 32 + i * 16 + l15) * 32 + quad * 8];
#pragma unroll
    for (int j = 0; j < 4; ++j)
      bfr[j] = *(const bf16x8*)&Bs[(j * 16 + l15) * 32 + quad * 8];
#pragma unroll
    for (int i = 0; i < 2; ++i)
#pragma unroll
      for (int j = 0; j < 4; ++j)
        acc[i][j] = __builtin_amdgcn_mfma_f32_16x16x32_bf16(af[i], bfr[j],
                                                            acc[i][j], 0, 0, 0);
    __syncthreads();
  }

#pragma unroll
  for (int i = 0; i < 2; ++i) {
    int row = row0 + wave * 32 + i * 16 + quad * 4;
#pragma unroll
    for (int j = 0; j < 4; ++j) {
      int col = nb + j * 16 + l15;
#pragma unroll
      for (int r = 0; r < 4; ++r)
        out[(size_t)(row + r) * D_MODEL + col] = acc[i][j][r];
    }
  }
}

// ---------------------------------------------------------------------------
extern "C" void kernel_launch(void* const* d_in, const int* in_sizes, int n_in,
                              void* d_out, int out_size, void* d_ws, size_t ws_size,
                              hipStream_t stream) {
  const float* X  = (const float*)d_in[0];
  const float* Wq = (const float*)d_in[1];
  const float* Wk = (const float*)d_in[2];
  const float* Wv = (const float*)d_in[3];
  const float* Wo = (const float*)d_in[4];
  const int*  pos = (const int*)d_in[5];
  float* out = (float*)d_out;

  char* w = (char*)d_ws;
  bf16* Xb  = (bf16*)w;  w += (size_t)M_ROWS * D_MODEL * 2;
  bf16* Wqb = (bf16*)w;  w += (size_t)D_MODEL * D_MODEL * 2;
  bf16* Wkb = (bf16*)w;  w += (size_t)D_MODEL * D_MODEL * 2;
  bf16* Wvb = (bf16*)w;  w += (size_t)D_MODEL * D_MODEL * 2;
  bf16* Wob = (bf16*)w;  w += (size_t)D_MODEL * D_MODEL * 2;
  bf16* Qb  = (bf16*)w;  w += (size_t)M_ROWS * D_MODEL * 2;
  bf16* Kb  = (bf16*)w;  w += (size_t)M_ROWS * D_MODEL * 2;
  bf16* VT  = (bf16*)w;  w += (size_t)M_ROWS * D_MODEL * 2;
  bf16* AO  = (bf16*)w;  w += (size_t)M_ROWS * D_MODEL * 2;

  cast_all<<<(NX + 4 * NW) / 256, 256, 0, stream>>>(X, Wq, Wk, Wv, Wo,
                                                    Xb, Wqb, Wkb, Wvb, Wob);
  qkv_gemm<<<dim3(M_ROWS / 256, 3 * D_MODEL / 256), 512, 0, stream>>>(
      Xb, Wqb, Wkb, Wvb, pos, Qb, Kb, VT);
  attn_kernel<<<dim3(B_SZ * NUM_HEADS, T_SZ / 64), 256, 0, stream>>>(
      Qb, Kb, VT, pos, AO);
  out_gemm<<<dim3(M_ROWS / 128, D_MODEL / 64), 256, 0, stream>>>(AO, Wob, out);
}